// Round 6
// baseline (346.497 us; speedup 1.0000x reference)
//
#include <hip/hip_runtime.h>
#include <hip/hip_fp16.h>
#include <stdint.h>

#define LOSS_IDX 8388608
#define IDX_BASE 8388609

typedef _Float16 half8 __attribute__((ext_vector_type(8)));
typedef float f32x4 __attribute__((ext_vector_type(4)));
typedef unsigned long long u64;

// ---- workspace layout (bytes) ----
#define E2_OFF    0            // 1024 * 4 code norms
#define ETILE_OFF 4096         // 32 images * 40960 B pre-tiled fp16 hi/lo emb
// etile image (qt,cc): [hi: 256 rows * 80 B][lo: 256 rows * 80 B]
// row = 32 c halfs in four 16B chunks, chunk XOR-swizzled by (row>>3)&3, +16B pad
#define ZTILE_OFF 1314816      // 256 qg * 131072 B pre-tiled fp16 hi/lo z
// ztile image (qg,cc): [hi: 128 q * 64 B][lo: 128 q * 64 B]; row q = 32 c halfs
// in A-fragment order: 16B chunk kq holds halfs c = cc*32+kq*8 .. +7.
// TOTAL ws needed: 1314816 + 33554432 = 34,869,248 B (~33.3 MiB).

static __device__ __forceinline__ unsigned fkey(float d) {
    unsigned u = __float_as_uint(d);
    return u ^ ((unsigned)(((int)u) >> 31) | 0x80000000u);
}

// ---------------------------------------------------------------------------
// KPREP: fused prep, 384 blocks x 512 thr.
//  blocks 0..255  : z pre-tile. Block qg reads its 128 q x 256 c slice of z_e,
//                   splits to fp16 hi/lo, writes ztile in A-frag order
//                   (thread t: q=t>>2, kq=t&3 -> 16B store at byte t*16:
//                   perfectly coalesced). Also zeroes the loss cell (blk 0).
//  blocks 256..383: e2 norms + etile images (byte-identical to old k0).
// ---------------------------------------------------------------------------
__global__ __launch_bounds__(512) void kprep(
    const float* __restrict__ z_e, const float* __restrict__ emb,
    float* __restrict__ e2, ushort* __restrict__ etile,
    ushort* __restrict__ ztile, float* __restrict__ out) {
    int t = threadIdx.x;
    int blk = blockIdx.x;
    if (blk < 256) {                               // ---- z pre-tile ----
        if (blk == 0 && t == 0) out[LOSS_IDX] = 0.f;
        int qg = blk, qbase = qg * 128;
        int b = qbase >> 10, hw0 = qbase & 1023;
        const float* zb = z_e + b * (256 * 1024) + hw0;
        int q = t >> 2, kq = t & 3;
        ushort* zt = ztile + qg * 65536;           // 131072 B image (ushorts)
        #pragma unroll
        for (int cc = 0; cc < 8; ++cc) {
            float v[8];
            #pragma unroll
            for (int e = 0; e < 8; ++e)
                v[e] = zb[(cc * 32 + kq * 8 + e) * 1024 + q];
            unsigned wh[4], wl[4];
            #pragma unroll
            for (int i = 0; i < 4; ++i) {
                __half h0 = __float2half(v[2 * i]);
                __half h1 = __float2half(v[2 * i + 1]);
                __half l0 = __float2half(v[2 * i] - __half2float(h0));
                __half l1 = __float2half(v[2 * i + 1] - __half2float(h1));
                wh[i] = (unsigned)__half_as_ushort(h0) | ((unsigned)__half_as_ushort(h1) << 16);
                wl[i] = (unsigned)__half_as_ushort(l0) | ((unsigned)__half_as_ushort(l1) << 16);
            }
            // hi plane at cc*8192 ushorts, lo plane +4096; thread slot q*32+kq*8
            ((uint4*)(zt + cc * 8192))[t] = make_uint4(wh[0], wh[1], wh[2], wh[3]);
            ((uint4*)(zt + cc * 8192 + 4096))[t] = make_uint4(wl[0], wl[1], wl[2], wl[3]);
        }
        return;
    }
    // ---- e prep (old k0, 65536 logical threads) ----
    int tid = (blk - 256) * 512 + t;               // 0..65535
    int code = tid >> 6;                           // 0..1023
    int lane = tid & 63;
    const float4 v4 = *(const float4*)&emb[code * 256 + lane * 4];
    float vv[4] = {v4.x, v4.y, v4.z, v4.w};
    float s = vv[0]*vv[0] + vv[1]*vv[1] + vv[2]*vv[2] + vv[3]*vv[3];
    #pragma unroll
    for (int off = 32; off > 0; off >>= 1) s += __shfl_down(s, off, 64);
    if (lane == 0) e2[code] = s;
    int cg = code >> 8, n = code & 255;            // 4 quarters of 256 codes
    int xs = (n >> 3) & 3;                         // row-octet XOR swizzle
    #pragma unroll
    for (int i = 0; i < 4; ++i) {
        int c = lane * 4 + i;
        float v = vv[i];
        __half h = __float2half(v);                       // RNE
        __half l = __float2half(v - __half2float(h));     // residual
        int cc = c >> 5, cw = c & 31;
        int ch = (cw >> 3) ^ xs;                          // swizzled 16B chunk
        int hoff = (cg * 8 + cc) * 20480 + n * 40 + ch * 8 + (cw & 7);
        etile[hoff] = __half_as_ushort(h);                // hi plane
        etile[hoff + 10240] = __half_as_ushort(l);        // lo plane
    }
}

// ---------------------------------------------------------------------------
// K2: one block per qg (grid 256 = CU count, ONE scheduling round).
// Block owns 128 queries x ALL 1024 codes: loops qt (4 code quarters) x cc
// (8 k-chunks) = 32 phases. Per phase: [a-frag global loads (regs, L2-hot,
// issued FIRST for in-order vmcnt) | stage_e next image (dbuf DMA, flies
// across the whole phase) | b-frag ds_reads | 48 MFMA] one barrier.
// acc[4][4] per qt; running u64 best[4][4] in regs across qt. In-block
// argmin (shuffle + LDS table, NO global atomics), then the same block
// writes indices/res/loss: k3, win64, and the 4x z redundancy are deleted.
// z^2 loss term recovered from hi+lo during the qt==0 pass (nqr==0 waves).
// ---------------------------------------------------------------------------
__global__ __launch_bounds__(512, 2) void k2_mfma(
    const float* __restrict__ e2g, const ushort* __restrict__ etile,
    const ushort* __restrict__ ztile, const float* __restrict__ emb,
    float* __restrict__ out) {
    __shared__ __attribute__((aligned(16))) ushort eb[2][20480]; // 81920 B
    __shared__ float e2_s[1024];
    __shared__ u64 tbl[4][128];
    __shared__ int lwin[128];
    __shared__ float red_s[2], red2_s[2];
    __shared__ __attribute__((aligned(16))) float lde[64 * 257]; // 65792 B

    int t = threadIdx.x, lane = t & 63, w = t >> 6;
    int qg = blockIdx.x, qbase = qg * 128;
    int b = qbase >> 10, hw0 = qbase & 1023;
    int qh = w >> 2, nqr = w & 3;       // 2x4 wave grid: 64 q x 64 codes/quarter
    int lm = lane & 15, kq = lane >> 4;

    e2_s[t] = e2g[t];
    e2_s[t + 512] = e2g[t + 512];

    const ushort* ztq = ztile + qg * 65536;

    u64 best[4][4];
    #pragma unroll
    for (int mt = 0; mt < 4; ++mt)
        #pragma unroll
        for (int r = 0; r < 4; ++r) best[mt][r] = ~0ull;

    auto stage_e = [&](int img, int buf) {
        const char* gsrc = (const char*)etile + (size_t)img * 40960;
        char* ldst = (char*)&eb[buf][0];
        #pragma unroll
        for (int i = 0; i < 5; ++i) {
            int off = (i * 512 + t) * 16;
            __builtin_amdgcn_global_load_lds(
                (const __attribute__((address_space(1))) unsigned int*)(gsrc + off),
                (__attribute__((address_space(3))) unsigned int*)(ldst + off),
                16, 0, 0);
        }
    };

    float z2acc = 0.f;
    stage_e(0, 0);
    __syncthreads();

    for (int qt = 0; qt < 4; ++qt) {
        f32x4 acc[4][4];
        #pragma unroll
        for (int mt = 0; mt < 4; ++mt)
            #pragma unroll
            for (int nt = 0; nt < 4; ++nt) acc[mt][nt] = (f32x4){0.f, 0.f, 0.f, 0.f};

        #pragma unroll
        for (int cc = 0; cc < 8; ++cc) {
            const int cur = cc & 1;
            // a-frags FIRST: oldest vmcnt slots -> MFMA waits vmcnt(5),
            // leaving the 5 stage-DMA ops in flight across the MFMA cluster.
            half8 ah[4], al[4];
            const ushort* za = ztq + cc * 8192;
            #pragma unroll
            for (int mt = 0; mt < 4; ++mt) {
                int q = qh * 64 + mt * 16 + lm;
                ah[mt] = *(const half8*)(za + q * 32 + kq * 8);
                al[mt] = *(const half8*)(za + 4096 + q * 32 + kq * 8);
            }
            __builtin_amdgcn_sched_barrier(0);     // pin a-loads before DMA
            int img = qt * 8 + cc;
            if (img < 31) stage_e(img + 1, cur ^ 1);
            half8 bh[4], bl[4];
            #pragma unroll
            for (int nt = 0; nt < 4; ++nt) {
                int n = nqr * 64 + nt * 16 + lm;
                int ech = kq ^ ((n >> 3) & 3);     // matches kprep layout
                bh[nt] = *(const half8*)&eb[cur][n * 40 + ech * 8];
                bl[nt] = *(const half8*)&eb[cur][10240 + n * 40 + ech * 8];
            }
            if (qt == 0 && nqr == 0) {             // z^2: each (q,c) once
                #pragma unroll
                for (int mt = 0; mt < 4; ++mt)
                    #pragma unroll
                    for (int e = 0; e < 8; ++e) {
                        float v = (float)ah[mt][e] + (float)al[mt][e];
                        z2acc = fmaf(v, v, z2acc);
                    }
            }
            __builtin_amdgcn_s_setprio(1);
            #pragma unroll
            for (int nt = 0; nt < 4; ++nt)
                #pragma unroll
                for (int mt = 0; mt < 4; ++mt)
                    acc[mt][nt] = __builtin_amdgcn_mfma_f32_16x16x32_f16(ah[mt], bh[nt], acc[mt][nt], 0, 0, 0);
            #pragma unroll
            for (int nt = 0; nt < 4; ++nt)
                #pragma unroll
                for (int mt = 0; mt < 4; ++mt)
                    acc[mt][nt] = __builtin_amdgcn_mfma_f32_16x16x32_f16(ah[mt], bl[nt], acc[mt][nt], 0, 0, 0);
            #pragma unroll
            for (int nt = 0; nt < 4; ++nt)
                #pragma unroll
                for (int mt = 0; mt < 4; ++mt)
                    acc[mt][nt] = __builtin_amdgcn_mfma_f32_16x16x32_f16(al[mt], bh[nt], acc[mt][nt], 0, 0, 0);
            __builtin_amdgcn_s_setprio(0);
            __syncthreads();                       // one barrier per phase
        }
        // fold this quarter into the running best (lane q = qh*64+mt*16+kq*4+r)
        #pragma unroll
        for (int mt = 0; mt < 4; ++mt)
            #pragma unroll
            for (int r = 0; r < 4; ++r)
                #pragma unroll
                for (int nt = 0; nt < 4; ++nt) {
                    int nloc = nqr * 64 + nt * 16 + lm;
                    float d = fmaf(-2.f, acc[mt][nt][r], e2_s[qt * 256 + nloc]);
                    u64 p = ((u64)fkey(d) << 32) | (unsigned)(qt * 256 + nloc);
                    if (p < best[mt][r]) best[mt][r] = p;
                }
    }

    // ---- in-block argmin: reduce 16 lm-lanes, then across nqr via LDS ----
    #pragma unroll
    for (int mt = 0; mt < 4; ++mt)
        #pragma unroll
        for (int r = 0; r < 4; ++r) {
            u64 bst = best[mt][r];
            #pragma unroll
            for (int m = 1; m <= 8; m <<= 1) {
                unsigned blo = __shfl_xor((unsigned)bst, m, 64);
                unsigned bhi = __shfl_xor((unsigned)(bst >> 32), m, 64);
                u64 p = ((u64)bhi << 32) | blo;
                if (p < bst) bst = p;
            }
            if (lm == 0) tbl[nqr][qh * 64 + mt * 16 + kq * 4 + r] = bst;
        }
    if (nqr == 0) {                                // z^2 block reduce
        #pragma unroll
        for (int off = 32; off > 0; off >>= 1) z2acc += __shfl_down(z2acc, off, 64);
        if (lane == 0) red2_s[qh] = z2acc;
    }
    __syncthreads();
    if (t < 128) {                                 // final winner per query
        u64 p = tbl[0][t];
        if (tbl[1][t] < p) p = tbl[1][t];
        if (tbl[2][t] < p) p = tbl[2][t];
        if (tbl[3][t] < p) p = tbl[3][t];
        int k = (int)(p & 0xFFFFFFFFull);
        lwin[t] = k;
        out[IDX_BASE + qbase + t] = (float)k;
        unsigned key = (unsigned)(p >> 32);        // d'win = e2 - 2 z.e
        unsigned u = (key & 0x80000000u) ? (key ^ 0x80000000u) : ~key;
        float dval = __uint_as_float(u);
        #pragma unroll
        for (int off = 32; off > 0; off >>= 1) dval += __shfl_down(dval, off, 64);
        if (lane == 0) red_s[w] = dval;
    }
    __syncthreads();
    if (t == 0)
        atomicAdd(&out[LOSS_IDX],
                  (red_s[0] + red_s[1] + red2_s[0] + red2_s[1]) * (1.25f / 8388608.f));

    // ---- output tail: gather emb[k*] and scatter res (two 64-q halves) ----
    #pragma unroll
    for (int half = 0; half < 2; ++half) {
        __syncthreads();
        for (int i = 0; i < 64; i += 2) {          // 2 rows x 256 c per iter
            int row = i + (t >> 8);
            lde[row * 257 + (t & 255)] = emb[lwin[half * 64 + row] * 256 + (t & 255)];
        }
        __syncthreads();
        float* rb = out + b * (256 * 1024) + (hw0 + half * 64);
        int j = t & 63, chi = t >> 6;              // 256 B contiguous per wave
        #pragma unroll 4
        for (int p2 = 0; p2 < 32; ++p2) {
            int c = p2 * 8 + chi;
            rb[c * 1024 + j] = lde[j * 257 + c];
        }
    }
}

// ---------------------------------------------------------------------------
extern "C" void kernel_launch(void* const* d_in, const int* in_sizes, int n_in,
                              void* d_out, int out_size, void* d_ws, size_t ws_size,
                              hipStream_t stream) {
    const float* z_e = (const float*)d_in[0];   // (32,256,32,32) fp32
    const float* emb = (const float*)d_in[1];   // (1024,256) fp32
    float* out = (float*)d_out;                 // res | loss | indices(float)
    float*  e2    = (float*)((char*)d_ws + E2_OFF);
    ushort* etile = (ushort*)((char*)d_ws + ETILE_OFF);
    ushort* ztile = (ushort*)((char*)d_ws + ZTILE_OFF);

    kprep<<<384, 512, 0, stream>>>(z_e, emb, e2, etile, ztile, out);
    k2_mfma<<<256, 512, 0, stream>>>(e2, etile, ztile, emb, out);
}

// Round 7
// 155.709 us; speedup vs baseline: 2.2253x; 2.2253x over previous
//
#include <hip/hip_runtime.h>
#include <hip/hip_bf16.h>
#include <hip/hip_fp16.h>
#include <stdint.h>

#define LOSS_IDX 8388608
#define IDX_BASE 8388609

typedef _Float16 half8 __attribute__((ext_vector_type(8)));
typedef float f32x4 __attribute__((ext_vector_type(4)));
typedef unsigned long long u64;

// ---- workspace layout (bytes) ----
#define WIN_OFF   0            // 32768 * 8  winner (key<<32 | k)
#define E2_OFF    262144       // 1024 * 4   code norms
#define ETILE_OFF 266240       // 16 images * 81920 B  pre-tiled fp16 hi/lo emb
// image (cg,cc): [hi: 512 rows * 80 B][lo: 512 rows * 80 B]; row = 32 c halfs + pad

static __device__ __forceinline__ unsigned fkey(float d) {
    unsigned u = __float_as_uint(d);
    return u ^ ((unsigned)(((int)u) >> 31) | 0x80000000u);
}

// ---------------------------------------------------------------------------
// K0: e2 norms, emb -> pre-tiled fp16 hi/lo planes, winner-table init, loss=0.
// One wave per code row. 256 blocks x 256 threads = 65536 threads.
// (ROUND-0 VERBATIM — best measured config.)
// ---------------------------------------------------------------------------
__global__ __launch_bounds__(256) void k0_prep(
    const float* __restrict__ emb, float* __restrict__ e2,
    ushort* __restrict__ etile, unsigned* __restrict__ win32,
    float* __restrict__ out) {
    int tid = blockIdx.x * 256 + threadIdx.x;      // 0..65535
    win32[tid] = 0xFFFFFFFFu;                      // win64 = all-ones
    if (tid == 0) out[LOSS_IDX] = 0.f;             // re-zero every call
    int code = tid >> 6;
    int lane = tid & 63;
    const float4 v4 = *(const float4*)&emb[code * 256 + lane * 4];
    float vv[4] = {v4.x, v4.y, v4.z, v4.w};
    float s = vv[0]*vv[0] + vv[1]*vv[1] + vv[2]*vv[2] + vv[3]*vv[3];
    #pragma unroll
    for (int off = 32; off > 0; off >>= 1) s += __shfl_down(s, off, 64);
    if (lane == 0) e2[code] = s;
    int cg = code >> 9, n = code & 511;
    #pragma unroll
    for (int i = 0; i < 4; ++i) {
        int c = lane * 4 + i;
        float v = vv[i];
        __half h = __float2half(v);                       // RNE
        __half l = __float2half(v - __half2float(h));     // residual
        int cc = c >> 5, cw = c & 31;
        int hoff = (cg * 8 + cc) * 40960 + n * 40 + (cw >> 3) * 8 + (cw & 7);
        etile[hoff] = __half_as_ushort(h);                // hi plane
        etile[hoff + 20480] = __half_as_ushort(l);        // lo plane
    }
}

// ---------------------------------------------------------------------------
// K2: fp16x3 MFMA distance GEMM + fused argmin.  (ROUND-0 VERBATIM — 78 us,
// unbeaten by 4 restructures: dbuf/2-phase, 3-pass MFMA order, 4-wave blocks,
// one-block-per-qg all matched or regressed. This is the local optimum for
// the 2-barrier staging structure at 1 block/CU.)
// ---------------------------------------------------------------------------
__global__ __launch_bounds__(512, 2) void k2_mfma(
    const float* __restrict__ z_e, const float* __restrict__ e2g,
    const ushort* __restrict__ etile, u64* __restrict__ win64,
    float* __restrict__ out) {
    __shared__ __attribute__((aligned(16))) ushort zh_s[128 * 40];
    __shared__ __attribute__((aligned(16))) ushort zl_s[128 * 40];
    __shared__ __attribute__((aligned(16))) ushort ehl_s[2 * 512 * 40];
    __shared__ float e2_s[512];
    __shared__ float red_s[8];

    int t = threadIdx.x;
    int lane = t & 63;
    int w = t >> 6;
    int cg = blockIdx.x & 1;        // code group: 512 codes
    int qg = blockIdx.x >> 1;       // query group: 128 queries
    int qbase = qg * 128;
    int b = qbase >> 10;
    int hw0 = qbase & 1023;
    const float* zb = z_e + b * (256 * 1024) + hw0;

    e2_s[t & 511] = e2g[cg * 512 + (t & 511)];

    f32x4 acc[4][8];
    #pragma unroll
    for (int mt = 0; mt < 4; ++mt)
        #pragma unroll
        for (int nt = 0; nt < 8; ++nt) acc[mt][nt] = (f32x4){0.f, 0.f, 0.f, 0.f};

    int qz = t & 127, sz = t >> 7;  // staging: q fixed per thread, 4 c-slots
    float z2acc = 0.f;
    int qh = w >> 2, nqr = w & 3;   // wave tile: 64 q x 128 codes
    int lm = lane & 15, kq = lane >> 4;

    for (int cc = 0; cc < 8; ++cc) {
        __syncthreads();
        // ---- stage e chunk: 81920 B contiguous DMA ----
        const char* gsrc = (const char*)(etile + (size_t)(cg * 8 + cc) * 40960);
        #pragma unroll
        for (int i = 0; i < 10; ++i) {
            int off = (i * 512 + t) * 16;
            __builtin_amdgcn_global_load_lds(
                (const __attribute__((address_space(1))) unsigned int*)(gsrc + off),
                (__attribute__((address_space(3))) unsigned int*)((char*)ehl_s + off),
                16, 0, 0);
        }
        // ---- stage z chunk: transpose + hi/lo split ----
        int cbase = cc * 32;
        #pragma unroll
        for (int i = 0; i < 4; ++i) {
            int c2v = i * 4 + sz;               // b32 slot 0..15
            int c = cbase + 2 * c2v;
            float v0 = zb[c * 1024 + qz];
            float v1 = zb[(c + 1) * 1024 + qz];
            z2acc = fmaf(v0, v0, z2acc);
            z2acc = fmaf(v1, v1, z2acc);
            __half h0 = __float2half(v0), h1 = __float2half(v1);
            __half l0 = __float2half(v0 - __half2float(h0));
            __half l1 = __float2half(v1 - __half2float(h1));
            unsigned wh = (unsigned)__half_as_ushort(h0) | ((unsigned)__half_as_ushort(h1) << 16);
            unsigned wl = (unsigned)__half_as_ushort(l0) | ((unsigned)__half_as_ushort(l1) << 16);
            int ch = (c2v >> 2) ^ ((qz >> 3) & 3);     // chunk XOR swizzle
            int idx = qz * 20 + ch * 4 + (c2v & 3);
            ((unsigned*)zh_s)[idx] = wh;
            ((unsigned*)zl_s)[idx] = wl;
        }
        __syncthreads();
        // ---- compute: one 32-c k-step ----
        half8 ah[4], al[4];
        #pragma unroll
        for (int mt = 0; mt < 4; ++mt) {
            int q = qh * 64 + mt * 16 + lm;
            int ch = kq ^ ((q >> 3) & 3);
            ah[mt] = *(const half8*)&zh_s[q * 40 + ch * 8];
            al[mt] = *(const half8*)&zl_s[q * 40 + ch * 8];
        }
        #pragma unroll
        for (int nt = 0; nt < 8; ++nt) {
            int n = nqr * 128 + nt * 16 + lm;
            half8 bh = *(const half8*)&ehl_s[n * 40 + kq * 8];
            half8 bl = *(const half8*)&ehl_s[20480 + n * 40 + kq * 8];
            #pragma unroll
            for (int mt = 0; mt < 4; ++mt) {
                acc[mt][nt] = __builtin_amdgcn_mfma_f32_16x16x32_f16(ah[mt], bh, acc[mt][nt], 0, 0, 0);
                acc[mt][nt] = __builtin_amdgcn_mfma_f32_16x16x32_f16(ah[mt], bl, acc[mt][nt], 0, 0, 0);
                acc[mt][nt] = __builtin_amdgcn_mfma_f32_16x16x32_f16(al[mt], bh, acc[mt][nt], 0, 0, 0);
            }
        }
    }

    // ---- argmin epilogue: C layout col=lane&15 (code), row=(lane>>4)*4+r (q)
    int lg = lane >> 4;
    #pragma unroll
    for (int mt = 0; mt < 4; ++mt)
        #pragma unroll
        for (int r = 0; r < 4; ++r) {
            int qloc = qh * 64 + mt * 16 + lg * 4 + r;
            u64 best = ~0ull;
            #pragma unroll
            for (int nt = 0; nt < 8; ++nt) {
                int nloc = nqr * 128 + nt * 16 + lm;
                float d = fmaf(-2.f, acc[mt][nt][r], e2_s[nloc]);
                u64 p = ((u64)fkey(d) << 32) | (unsigned)(cg * 512 + nloc);
                if (p < best) best = p;
            }
            #pragma unroll
            for (int m = 1; m <= 8; m <<= 1) {     // reduce over 16 code-lanes
                unsigned blo = __shfl_xor((unsigned)best, m, 64);
                unsigned bhi = __shfl_xor((unsigned)(best >> 32), m, 64);
                u64 p = ((u64)bhi << 32) | blo;
                if (p < best) best = p;
            }
            if (lm == 0) atomicMin(&win64[qbase + qloc], best);
        }

    // ---- sum(z^2) loss contribution (count once: cg==0 blocks) ----
    #pragma unroll
    for (int off = 32; off > 0; off >>= 1) z2acc += __shfl_down(z2acc, off, 64);
    if (lane == 0) red_s[w] = z2acc;
    __syncthreads();
    if (t == 0 && cg == 0) {
        float s = 0.f;
        #pragma unroll
        for (int i = 0; i < 8; ++i) s += red_s[i];
        atomicAdd(&out[LOSS_IDX], s * (1.25f / 8388608.f));
    }
}

// ---------------------------------------------------------------------------
// K3: res = emb[k*] scattered to (b,c,h,w); indices as float; loss part 2
// recovered from the winner key (d'win = e2 - 2 z.e = (zq-z)^2 - z^2).
// ROUND-7: 512 threads (8 waves, was 4) — 2 emb rows gathered per iter
// (32 iters, was 64) and 8 c-lanes per scatter iter (32 iters, was 64).
// Round-5's MfmaUtil-dilution arithmetic proved the output stage is
// latency/parallelism-bound (floor ~11 us, measured ~28): double the
// resident waves, halve the dependent-loop lengths.
// ---------------------------------------------------------------------------
__global__ __launch_bounds__(512, 2) void k3_out(
    const float* __restrict__ emb, const u64* __restrict__ win64,
    float* __restrict__ out) {
    __shared__ float lde[64 * 257];
    __shared__ int lwin[64];
    int t = threadIdx.x;
    int qbase = blockIdx.x * 64;
    int b = qbase >> 10;
    int hw0 = qbase & 1023;
    if (t < 64) {                                  // wave 0 only (uniform)
        u64 p = win64[qbase + t];
        int k = (int)(p & 0xFFFFFFFFull);
        lwin[t] = k;
        out[IDX_BASE + qbase + t] = (float)k;
        unsigned key = (unsigned)(p >> 32);
        unsigned u = (key & 0x80000000u) ? (key ^ 0x80000000u) : ~key;
        float dval = __uint_as_float(u);
        #pragma unroll
        for (int off = 32; off > 0; off >>= 1) dval += __shfl_down(dval, off, 64);
        if (t == 0) atomicAdd(&out[LOSS_IDX], dval * (1.25f / 8388608.f));
    }
    __syncthreads();
    #pragma unroll 4
    for (int i = 0; i < 64; i += 2) {              // 2 rows x 256 c per iter
        int row = i + (t >> 8);
        lde[row * 257 + (t & 255)] = emb[lwin[row] * 256 + (t & 255)];
    }
    __syncthreads();
    float* rb = out + b * (256 * 1024) + hw0;
    int j = t & 63, chi = t >> 6;                  // 8 waves, 8 c per iter
    #pragma unroll 8
    for (int p = 0; p < 32; ++p) {
        int c = p * 8 + chi;
        rb[c * 1024 + j] = lde[j * 257 + c];       // 2-way banks (free)
    }
}

// ---------------------------------------------------------------------------
extern "C" void kernel_launch(void* const* d_in, const int* in_sizes, int n_in,
                              void* d_out, int out_size, void* d_ws, size_t ws_size,
                              hipStream_t stream) {
    const float* z_e = (const float*)d_in[0];   // (32,256,32,32) fp32
    const float* emb = (const float*)d_in[1];   // (1024,256) fp32
    float* out = (float*)d_out;                 // res | loss | indices(float)
    u64*    win   = (u64*)((char*)d_ws + WIN_OFF);
    float*  e2    = (float*)((char*)d_ws + E2_OFF);
    ushort* etile = (ushort*)((char*)d_ws + ETILE_OFF);

    k0_prep<<<256, 256, 0, stream>>>(emb, e2, etile, (unsigned*)win, out);
    k2_mfma<<<512, 512, 0, stream>>>(z_e, e2, etile, win, out);
    k3_out <<<512, 512, 0, stream>>>(emb, win, out);
}